// Round 3
// baseline (852.860 us; speedup 1.0000x reference)
//
#include <hip/hip_runtime.h>
#include <stdint.h>

// ---------- types ----------
typedef __attribute__((ext_vector_type(8)))  __bf16 bf16x8;   // MFMA A/B frag (4 VGPRs)
typedef __attribute__((ext_vector_type(16))) float  f32x16;   // 32x32 MFMA C/D frag
typedef unsigned short u16;
typedef __attribute__((ext_vector_type(8))) unsigned short u16x8;

#define GLOBAL_AS __attribute__((address_space(1)))
#define LDS_AS    __attribute__((address_space(3)))

__device__ __forceinline__ void load_lds16(const void* g, void* l) {
    __builtin_amdgcn_global_load_lds((const GLOBAL_AS void*)g, (LDS_AS void*)l, 16, 0, 0);
}

__device__ __forceinline__ u16 f2bf(float f) {
    union { float f; uint32_t u; } v; v.f = f;
    uint32_t r = v.u + 0x7FFFu + ((v.u >> 16) & 1u);   // RNE
    return (u16)(r >> 16);
}
__device__ __forceinline__ float b2f(u16 b) {
    union { uint32_t u; float f; } v; v.u = ((uint32_t)b) << 16;
    return v.f;
}

// ---------- aux: fp32 -> bf16 convert with zero-padding ----------
__global__ void k_conv_pad(const float* __restrict__ in, u16* __restrict__ out,
                           int rIn, int cIn, int cOut, int total8) {
    int idx = blockIdx.x * blockDim.x + threadIdx.x;
    if (idx >= total8) return;
    int c8n = cOut >> 3;
    int r  = idx / c8n;
    int c0 = (idx - r * c8n) << 3;
    u16x8 o;
#pragma unroll
    for (int j = 0; j < 8; ++j) {
        int c = c0 + j;
        o[j] = (r < rIn && c < cIn) ? f2bf(in[(size_t)r * cIn + c]) : (u16)0;
    }
    *(u16x8*)(out + (size_t)r * cOut + c0) = o;
}

// ---------- aux: fp32 [kIn x nIn] -> bf16 transposed [nOut x kOut], zero-padded ----------
__global__ void k_transpose_conv(const float* __restrict__ in, u16* __restrict__ out,
                                 int kIn, int nIn, int kOut) {
    __shared__ float tile[32][33];
    int k0 = blockIdx.x * 32, n0 = blockIdx.y * 32;
    int tx = threadIdx.x, ty = threadIdx.y;   // block (32,8)
#pragma unroll
    for (int i = 0; i < 4; ++i) {
        int k = k0 + ty + i * 8, n = n0 + tx;
        tile[ty + i * 8][tx] = (k < kIn && n < nIn) ? in[(size_t)k * nIn + n] : 0.f;
    }
    __syncthreads();
#pragma unroll
    for (int i = 0; i < 4; ++i) {
        int n = n0 + ty + i * 8, k = k0 + tx;
        out[(size_t)n * kOut + k] = f2bf(tile[tx][ty + i * 8]);
    }
}

// ---------- old 128x128 kernel (kept for G3: N=2048 gives only 128 wgs at 256^2) ----------
template <int MODE>
__global__ __launch_bounds__(256, 4) void k_gemm_bt(
    const u16* __restrict__ A, const u16* __restrict__ B,
    const u16* __restrict__ bias, void* __restrict__ Cv,
    int K, int ldc, int mReal, int nReal) {
    (void)bias;
    __shared__ __align__(16) char lds[32768];
    char* As = lds;
    char* Bs = lds + 16384;

    const int tid  = threadIdx.x;
    const int w    = tid >> 6, lane = tid & 63;
    const int l31  = lane & 31, hi = lane >> 5;
    const int wm   = (w & 1) * 64, wn = (w >> 1) * 64;
    const int bm   = blockIdx.y * 128, bn = blockIdx.x * 128;

    const int srcRow = tid >> 3;
    const int srcCol = (tid & 7) ^ (srcRow & 7);
    const u16* aSrc = A + (size_t)(bm + srcRow) * K + (srcCol << 3);
    const u16* bSrc = B + (size_t)(bn + srcRow) * K + (srcCol << 3);
    char* aDst = As + ((tid & ~63) << 4);
    char* bDst = Bs + ((tid & ~63) << 4);

    const int aRow0 = (wm + l31) * 128;
    const int aRow1 = (wm + 32 + l31) * 128;
    const int bRow0 = (wn + l31) * 128;
    const int bRow1 = (wn + 32 + l31) * 128;

    f32x16 acc[2][2];
#pragma unroll
    for (int i = 0; i < 2; ++i)
#pragma unroll
        for (int j = 0; j < 2; ++j) acc[i][j] = (f32x16)(0.f);

    for (int k0 = 0; k0 < K; k0 += 64) {
#pragma unroll
        for (int t = 0; t < 4; ++t) {
            load_lds16(aSrc + (size_t)(t * 32) * K, aDst + t * 4096);
            load_lds16(bSrc + (size_t)(t * 32) * K, bDst + t * 4096);
        }
        aSrc += 64; bSrc += 64;
        __syncthreads();
#pragma unroll
        for (int ks = 0; ks < 4; ++ks) {
            const int swz = (((ks * 2 + hi) ^ (l31 & 7)) << 4);
            bf16x8 af[2], bfr[2];
            af[0]  = *(const bf16x8*)(As + aRow0 + swz);
            af[1]  = *(const bf16x8*)(As + aRow1 + swz);
            bfr[0] = *(const bf16x8*)(Bs + bRow0 + swz);
            bfr[1] = *(const bf16x8*)(Bs + bRow1 + swz);
#pragma unroll
            for (int mi = 0; mi < 2; ++mi)
#pragma unroll
                for (int ni = 0; ni < 2; ++ni)
                    acc[mi][ni] = __builtin_amdgcn_mfma_f32_32x32x16_bf16(
                        af[mi], bfr[ni], acc[mi][ni], 0, 0, 0);
        }
        __syncthreads();
    }

    float bv[2];
    if (MODE >= 1) {
#pragma unroll
        for (int ni = 0; ni < 2; ++ni) bv[ni] = b2f(bias[bn + wn + ni * 32 + l31]);
    }
#pragma unroll
    for (int mi = 0; mi < 2; ++mi) {
#pragma unroll
        for (int reg = 0; reg < 16; ++reg) {
            int row = bm + wm + mi * 32 + (reg & 3) + 8 * (reg >> 2) + 4 * hi;
#pragma unroll
            for (int ni = 0; ni < 2; ++ni) {
                int col = bn + wn + ni * 32 + l31;
                float v = acc[mi][ni][reg];
                if (MODE == 0) {
                    if (row < mReal && col < nReal)
                        ((u16*)Cv)[(size_t)row * ldc + col] = f2bf(v);
                } else if (MODE == 1) {
                    v += bv[ni];
                    v = v > 0.f ? v : 0.f;
                    ((u16*)Cv)[(size_t)row * ldc + col] = f2bf(v);
                } else {
                    ((float*)Cv)[(size_t)row * ldc + col] = v + bv[ni];
                }
            }
        }
    }
}

// ---------- 256x256 pipelined GEMM v3: FRAGMENT-MAJOR LDS (conflict-free ds_read) ----------
// R2 post-mortem: MfmaUtil pinned at ~30% by a structural 4-way bank conflict —
// 32x32 frag reads put 32 lanes on 32 different 128-B rows at the same 16-B column
// slot; rows are exactly one bank period, so chunk^(row&7) swizzles can't fix rows
// 8 apart (SQ_LDS_BANK_CONFLICT invariant across R1/R2 = 1.87e7 ~ 4 cyc/read).
// Fix: stage so each MFMA fragment is 1024 CONTIGUOUS LDS bytes in lane order:
//   LDS = [8 blocks(32 rows)][4 k-slices][lane*16], A at 0, B at +32768 per buf.
// ds_read addr = frag_base + lane*16  -> perfectly sequential, zero conflicts.
// global_load_lds writes wave-linear, so staging wave w sweep t fills region
// r = w + 8t = (block mb = (w>>2)+2t, slice p = w&3); lane Y fetches
// A[bm + mb*32 + (Y&31)][k0 + p*16 + (Y>>5)*8] (32-B row granules; L2 coalesces;
// async-latency tolerant). Read side: frag(mi,p) at (wr*4+mi)*4096 + p*1024.
// Also: one-phase-ahead register prefetch (two named frag sets, static indexing)
// so each phase's 6 reads are issued a phase before their MFMAs.
// Sync ledger (2 barriers / 2-tile iter) unchanged from R2:
//   B_B: lgkm0 (buf0 reads drained) + vmcnt0 (buf1 stage landed) -> restage buf0
//   B_A: lgkm0 (buf1 reads drained) + vmcnt0 (buf0 stage landed) -> loop, stage buf1

#define BARRIER() do { asm volatile("" ::: "memory"); \
                       __builtin_amdgcn_s_barrier(); \
                       asm volatile("" ::: "memory"); } while (0)
#define LGKM0()   do { asm volatile("s_waitcnt lgkmcnt(0)" ::: "memory"); \
                       __builtin_amdgcn_sched_barrier(0); } while (0)
#define VMCNT0()  do { asm volatile("s_waitcnt vmcnt(0)" ::: "memory"); \
                       __builtin_amdgcn_sched_barrier(0); } while (0)

// 8 global_load_lds: 4 A-sweeps + 4 B-sweeps, frag-major regions (see header comment)
#define STAGE8(bb, koff) do { \
    _Pragma("unroll") for (int t = 0; t < 4; ++t) \
        load_lds16(aS + (koff) + (size_t)(t * 64) * K, (bb) + wOff + t * 8192); \
    _Pragma("unroll") for (int t = 0; t < 4; ++t) \
        load_lds16(bS + (koff) + (size_t)(t * 64) * K, (bb) + 32768 + wOff + t * 8192); \
} while (0)

// 6 conflict-free frag reads for k-slice p
#define RD6(bb, p, FA, FB) do { \
    FA[0] = *(const bf16x8*)((bb) + aB +     0 + (p) * 1024); \
    FA[1] = *(const bf16x8*)((bb) + aB +  4096 + (p) * 1024); \
    FA[2] = *(const bf16x8*)((bb) + aB +  8192 + (p) * 1024); \
    FA[3] = *(const bf16x8*)((bb) + aB + 12288 + (p) * 1024); \
    FB[0] = *(const bf16x8*)((bb) + bB +     0 + (p) * 1024); \
    FB[1] = *(const bf16x8*)((bb) + bB +  4096 + (p) * 1024); \
} while (0)

#define MM8(FA, FB) do { \
    __builtin_amdgcn_s_setprio(1); \
    acc[0][0] = __builtin_amdgcn_mfma_f32_32x32x16_bf16(FA[0], FB[0], acc[0][0], 0, 0, 0); \
    acc[1][0] = __builtin_amdgcn_mfma_f32_32x32x16_bf16(FA[1], FB[0], acc[1][0], 0, 0, 0); \
    acc[2][0] = __builtin_amdgcn_mfma_f32_32x32x16_bf16(FA[2], FB[0], acc[2][0], 0, 0, 0); \
    acc[3][0] = __builtin_amdgcn_mfma_f32_32x32x16_bf16(FA[3], FB[0], acc[3][0], 0, 0, 0); \
    acc[0][1] = __builtin_amdgcn_mfma_f32_32x32x16_bf16(FA[0], FB[1], acc[0][1], 0, 0, 0); \
    acc[1][1] = __builtin_amdgcn_mfma_f32_32x32x16_bf16(FA[1], FB[1], acc[1][1], 0, 0, 0); \
    acc[2][1] = __builtin_amdgcn_mfma_f32_32x32x16_bf16(FA[2], FB[1], acc[2][1], 0, 0, 0); \
    acc[3][1] = __builtin_amdgcn_mfma_f32_32x32x16_bf16(FA[3], FB[1], acc[3][1], 0, 0, 0); \
    __builtin_amdgcn_s_setprio(0); \
} while (0)

template <int MODE>
__global__ __launch_bounds__(512, 2) void k_gemm256(
    const u16* __restrict__ A, const u16* __restrict__ B,
    const u16* __restrict__ bias, void* __restrict__ Cv,
    int K, int ldc, int mReal, int nReal, int gx, int nTiles) {
    __shared__ __align__(16) char lds[131072];

    const int tid  = threadIdx.x;
    const int w    = tid >> 6, lane = tid & 63;
    const int l31  = lane & 31, hi = lane >> 5;
    const int wr   = w & 1, wc = w >> 1;            // 2 M-waves x 4 N-waves

    // XCD-chunked swizzle (grid divisible by 8): contiguous tile chunk per XCD
    const int cpx = (int)gridDim.x >> 3;
    const int wg0 = ((int)blockIdx.x & 7) * cpx + ((int)blockIdx.x >> 3);

    char* const buf0 = lds;            // frag-major: A [32KB] then B [32KB]
    char* const buf1 = lds + 65536;

    // staging geometry (frag-major; see header comment)
    const int srcRowT = ((w >> 2) * 32) + l31;       // +64t per sweep
    const int kOffT   = (w & 3) * 16 + (hi << 3);
    const int wOff    = w * 1024;                    // wave-uniform LDS region base

    // conflict-free read bases
    const int aB = wr * 16384 + lane * 16;
    const int bB = 32768 + wc * 8192 + lane * 16;

    const int nIt = K >> 7;            // K-tile pairs (all K multiples of 128)

    for (int v = wg0; v < nTiles; v += (int)gridDim.x) {
        const int bm = (v / gx) * 256;
        const int bn = (v % gx) * 256;
        const u16* const aS = A + (size_t)(bm + srcRowT) * K + kOffT;
        const u16* const bS = B + (size_t)(bn + srcRowT) * K + kOffT;

        f32x16 acc[4][2];
#pragma unroll
        for (int i = 0; i < 4; ++i)
#pragma unroll
            for (int j = 0; j < 2; ++j) acc[i][j] = (f32x16)(0.f);

        bf16x8 xa[4], xb[2], ya[4], yb[2];

        // prologue: tile 0 -> buf0
        STAGE8(buf0, 0);
        VMCNT0();
        BARRIER();

        size_t ko = 0;
#pragma unroll 1
        for (int it = 0; it < nIt; ++it) {
            STAGE8(buf1, ko + 64);           // buf1 free since B_A
            // ----- tile 2*it from buf0 -----
            RD6(buf0, 0, xa, xb);
            RD6(buf0, 1, ya, yb);
            MM8(xa, xb);
            RD6(buf0, 2, xa, xb);
            MM8(ya, yb);
            RD6(buf0, 3, ya, yb);
            MM8(xa, xb);
            LGKM0(); VMCNT0(); BARRIER();    // B_B: buf0 drained, buf1 landed
            if (it + 1 < nIt) { STAGE8(buf0, ko + 128); }
            MM8(ya, yb);                     // regs only; overlaps buf1 p0 latency
            // ----- tile 2*it+1 from buf1 -----
            RD6(buf1, 0, xa, xb);
            RD6(buf1, 1, ya, yb);
            MM8(xa, xb);
            RD6(buf1, 2, xa, xb);
            MM8(ya, yb);
            RD6(buf1, 3, ya, yb);
            MM8(xa, xb);
            LGKM0(); VMCNT0(); BARRIER();    // B_A: buf1 drained, buf0 landed
            MM8(ya, yb);
            ko += 128;
        }

        // epilogue. 32x32 C/D layout: col = lane&31, row = (reg&3) + 8*(reg>>2) + 4*hi
        float bv[2];
        if (MODE >= 1) {
#pragma unroll
            for (int ni = 0; ni < 2; ++ni) bv[ni] = b2f(bias[bn + wc * 64 + ni * 32 + l31]);
        }
#pragma unroll
        for (int mi = 0; mi < 4; ++mi) {
#pragma unroll
            for (int reg = 0; reg < 16; ++reg) {
                const int row = bm + wr * 128 + mi * 32 + (reg & 3) + 8 * (reg >> 2) + 4 * hi;
#pragma unroll
                for (int ni = 0; ni < 2; ++ni) {
                    const int col = bn + wc * 64 + ni * 32 + l31;
                    float vv = acc[mi][ni][reg];
                    if (MODE == 0) {
                        if (row < mReal && col < nReal)
                            ((u16*)Cv)[(size_t)row * ldc + col] = f2bf(vv);
                    } else if (MODE == 1) {
                        vv += bv[ni];
                        vv = vv > 0.f ? vv : 0.f;
                        ((u16*)Cv)[(size_t)row * ldc + col] = f2bf(vv);
                    } else {
                        ((float*)Cv)[(size_t)row * ldc + col] = vv + bv[ni];
                    }
                }
            }
        }
    }
}

// ---------- launch ----------
// Sizes: D_IN=2048, D_H=4096, D_OUT=2048, B=4096; SIZE_N=5794, SIZE_M=2897
// Padded GEMM0 dims: M=N=5888 (23*256), K=2944 (23*128)
// Vf flat unpack offsets (elems):
//   W1 @ 0, b1 @ 8388608, W2 @ 8392704, b2 @ 25169920, W3 @ 25174016, b3 @ 33562624
extern "C" void kernel_launch(void* const* d_in, const int* in_sizes, int n_in,
                              void* d_out, int out_size, void* d_ws, size_t ws_size,
                              hipStream_t stream) {
    (void)in_sizes; (void)n_in; (void)out_size; (void)ws_size;
    const float* x  = (const float*)d_in[0];
    const float* V1 = (const float*)d_in[1];
    const float* V2 = (const float*)d_in[2];

    char* ws = (char*)d_ws;
    u16* Vf   = (u16*)(ws);                            // 5794*5794 bf16 -> 67,140,872 B
    u16* V1b  = (u16*)(ws + 67141120);                 // [5888 x 2944] bf16 = 34,668,544 B
    u16* V2bT = (u16*)(ws + 67141120 + 34668544);      // [5888 x 2944] bf16
    u16* Xb   = (u16*)(ws + 67141120 + 2 * 34668544);  // [4096 x 2048] bf16
    u16* H1   = V1b;   // dead after GEMM0
    u16* H2   = V2bT;

    k_conv_pad<<<8464, 256, 0, stream>>>(V1, V1b, 5794, 2897, 2944, 5888 * 2944 / 8);
    k_transpose_conv<<<dim3(92, 184), dim3(32, 8), 0, stream>>>(V2, V2bT, 2897, 5794, 2944);
    k_conv_pad<<<4096, 256, 0, stream>>>(x, Xb, 4096, 2048, 2048, 4096 * 2048 / 8);

    // G0: Vf = V1 @ V2  (padded 5888x5888x2944; 529 tiles over 512 blocks -> 2 rounds)
    k_gemm256<0><<<512, 512, 0, stream>>>(V1b, V2bT, nullptr, Vf,
                                          2944, 5794, 5794, 5794, 23, 529);
    // G1: H1 = relu(Xb @ W1^T + b1)   [4096x4096], K=2048 (256 tiles, exact 1 round)
    k_gemm256<1><<<256, 512, 0, stream>>>(Xb, Vf + 0, Vf + 8388608, H1,
                                          2048, 4096, 4096, 4096, 16, 256);
    // G2: H2 = relu(H1 @ W2^T + b2)   [4096x4096], K=4096
    k_gemm256<1><<<256, 512, 0, stream>>>(H1, Vf + 8392704, Vf + 25169920, H2,
                                          4096, 4096, 4096, 4096, 16, 256);
    // G3: out = H2 @ W3^T + b3        [4096x2048] fp32, K=4096 (128^2 kernel: 512 wgs)
    k_gemm_bt<2><<<dim3(16, 32), 256, 0, stream>>>(H2, Vf + 25174016, Vf + 33562624, d_out,
                                                   4096, 2048, 4096, 2048);
}

// Round 4
// 752.569 us; speedup vs baseline: 1.1333x; 1.1333x over previous
//
#include <hip/hip_runtime.h>
#include <stdint.h>

// ---------- types ----------
typedef __attribute__((ext_vector_type(8)))  __bf16 bf16x8;   // MFMA A/B frag (4 VGPRs)
typedef __attribute__((ext_vector_type(16))) float  f32x16;   // 32x32 MFMA C/D frag
typedef unsigned short u16;
typedef __attribute__((ext_vector_type(8))) unsigned short u16x8;

#define GLOBAL_AS __attribute__((address_space(1)))
#define LDS_AS    __attribute__((address_space(3)))

__device__ __forceinline__ void load_lds16(const void* g, void* l) {
    __builtin_amdgcn_global_load_lds((const GLOBAL_AS void*)g, (LDS_AS void*)l, 16, 0, 0);
}

__device__ __forceinline__ u16 f2bf(float f) {
    union { float f; uint32_t u; } v; v.f = f;
    uint32_t r = v.u + 0x7FFFu + ((v.u >> 16) & 1u);   // RNE
    return (u16)(r >> 16);
}
__device__ __forceinline__ float b2f(u16 b) {
    union { uint32_t u; float f; } v; v.u = ((uint32_t)b) << 16;
    return v.f;
}

// ---------- aux: fp32 -> bf16 convert with zero-padding ----------
__global__ void k_conv_pad(const float* __restrict__ in, u16* __restrict__ out,
                           int rIn, int cIn, int cOut, int total8) {
    int idx = blockIdx.x * blockDim.x + threadIdx.x;
    if (idx >= total8) return;
    int c8n = cOut >> 3;
    int r  = idx / c8n;
    int c0 = (idx - r * c8n) << 3;
    u16x8 o;
#pragma unroll
    for (int j = 0; j < 8; ++j) {
        int c = c0 + j;
        o[j] = (r < rIn && c < cIn) ? f2bf(in[(size_t)r * cIn + c]) : (u16)0;
    }
    *(u16x8*)(out + (size_t)r * cOut + c0) = o;
}

// ---------- aux: fp32 [kIn x nIn] -> bf16 transposed [nOut x kOut], zero-padded ----------
__global__ void k_transpose_conv(const float* __restrict__ in, u16* __restrict__ out,
                                 int kIn, int nIn, int kOut) {
    __shared__ float tile[32][33];
    int k0 = blockIdx.x * 32, n0 = blockIdx.y * 32;
    int tx = threadIdx.x, ty = threadIdx.y;   // block (32,8)
#pragma unroll
    for (int i = 0; i < 4; ++i) {
        int k = k0 + ty + i * 8, n = n0 + tx;
        tile[ty + i * 8][tx] = (k < kIn && n < nIn) ? in[(size_t)k * nIn + n] : 0.f;
    }
    __syncthreads();
#pragma unroll
    for (int i = 0; i < 4; ++i) {
        int n = n0 + ty + i * 8, k = k0 + tx;
        out[(size_t)n * kOut + k] = f2bf(tile[tx][ty + i * 8]);
    }
}

// ---------- old 128x128 kernel (kept for G3: proven ~97us at 4 blocks/CU) ----------
template <int MODE>
__global__ __launch_bounds__(256, 4) void k_gemm_bt(
    const u16* __restrict__ A, const u16* __restrict__ B,
    const u16* __restrict__ bias, void* __restrict__ Cv,
    int K, int ldc, int mReal, int nReal) {
    (void)bias;
    __shared__ __align__(16) char lds[32768];
    char* As = lds;
    char* Bs = lds + 16384;

    const int tid  = threadIdx.x;
    const int w    = tid >> 6, lane = tid & 63;
    const int l31  = lane & 31, hi = lane >> 5;
    const int wm   = (w & 1) * 64, wn = (w >> 1) * 64;
    const int bm   = blockIdx.y * 128, bn = blockIdx.x * 128;

    const int srcRow = tid >> 3;
    const int srcCol = (tid & 7) ^ (srcRow & 7);
    const u16* aSrc = A + (size_t)(bm + srcRow) * K + (srcCol << 3);
    const u16* bSrc = B + (size_t)(bn + srcRow) * K + (srcCol << 3);
    char* aDst = As + ((tid & ~63) << 4);
    char* bDst = Bs + ((tid & ~63) << 4);

    const int aRow0 = (wm + l31) * 128;
    const int aRow1 = (wm + 32 + l31) * 128;
    const int bRow0 = (wn + l31) * 128;
    const int bRow1 = (wn + 32 + l31) * 128;

    f32x16 acc[2][2];
#pragma unroll
    for (int i = 0; i < 2; ++i)
#pragma unroll
        for (int j = 0; j < 2; ++j) acc[i][j] = (f32x16)(0.f);

    for (int k0 = 0; k0 < K; k0 += 64) {
#pragma unroll
        for (int t = 0; t < 4; ++t) {
            load_lds16(aSrc + (size_t)(t * 32) * K, aDst + t * 4096);
            load_lds16(bSrc + (size_t)(t * 32) * K, bDst + t * 4096);
        }
        aSrc += 64; bSrc += 64;
        __syncthreads();
#pragma unroll
        for (int ks = 0; ks < 4; ++ks) {
            const int swz = (((ks * 2 + hi) ^ (l31 & 7)) << 4);
            bf16x8 af[2], bfr[2];
            af[0]  = *(const bf16x8*)(As + aRow0 + swz);
            af[1]  = *(const bf16x8*)(As + aRow1 + swz);
            bfr[0] = *(const bf16x8*)(Bs + bRow0 + swz);
            bfr[1] = *(const bf16x8*)(Bs + bRow1 + swz);
#pragma unroll
            for (int mi = 0; mi < 2; ++mi)
#pragma unroll
                for (int ni = 0; ni < 2; ++ni)
                    acc[mi][ni] = __builtin_amdgcn_mfma_f32_32x32x16_bf16(
                        af[mi], bfr[ni], acc[mi][ni], 0, 0, 0);
        }
        __syncthreads();
    }

    float bv[2];
    if (MODE >= 1) {
#pragma unroll
        for (int ni = 0; ni < 2; ++ni) bv[ni] = b2f(bias[bn + wn + ni * 32 + l31]);
    }
#pragma unroll
    for (int mi = 0; mi < 2; ++mi) {
#pragma unroll
        for (int reg = 0; reg < 16; ++reg) {
            int row = bm + wm + mi * 32 + (reg & 3) + 8 * (reg >> 2) + 4 * hi;
#pragma unroll
            for (int ni = 0; ni < 2; ++ni) {
                int col = bn + wn + ni * 32 + l31;
                float v = acc[mi][ni][reg];
                if (MODE == 0) {
                    if (row < mReal && col < nReal)
                        ((u16*)Cv)[(size_t)row * ldc + col] = f2bf(v);
                } else if (MODE == 1) {
                    v += bv[ni];
                    v = v > 0.f ? v : 0.f;
                    ((u16*)Cv)[(size_t)row * ldc + col] = f2bf(v);
                } else {
                    ((float*)Cv)[(size_t)row * ldc + col] = v + bv[ni];
                }
            }
        }
    }
}

// ---------- 256x128 co-resident pipelined GEMM v4 ----------
// R3 post-mortem: R2/R3 ran 1 block/CU (128 KiB LDS) — a single 8-wave
// barrier-lockstep block per CU has nothing to cover its stage drains
// (Occupancy 16.4% = 25% waves x 0.66 grid-fill; G1/G2 at 1 round crawl
// at ~26% MFMA for the same reason). Fix: 2 independent blocks/CU.
//   tile 256x128, 256 threads (4 waves, 2x2 grid, per-wave 128x64 as in R2),
//   BK=32 double-buffered -> LDS 48 KiB, launch_bounds(256,2), VGPR ~200.
// Staging: R2's coalesced pattern (8 rows x 64B contiguous per wave sweep),
// global_load_lds width 16, pre-swizzled source chunk c ^= (row>>1)&3 and the
// same XOR on ds_read (rule #21) -> even 8-lanes-per-bank-quad on every read.
// Sync ledger (2 barriers per 64-K pair), per-wave lgkmcnt(0)+vmcnt(0) ahead
// of each barrier:
//   B_B: all waves drained buf0 reads + buf1 stage landed -> restage buf0
//   B_A: all waves drained buf1 reads + buf0 stage landed -> loop, stage buf1
// Grids: G0 23x46=1058 (HW backfill, ~65us tail quantum), G1/G2 16x32=512
// (exactly 2/CU, one round, no tail).

#define BARRIER() do { asm volatile("" ::: "memory"); \
                       __builtin_amdgcn_s_barrier(); \
                       asm volatile("" ::: "memory"); } while (0)
#define LGKM0()   do { asm volatile("s_waitcnt lgkmcnt(0)" ::: "memory"); \
                       __builtin_amdgcn_sched_barrier(0); } while (0)
#define VMCNT0()  do { asm volatile("s_waitcnt vmcnt(0)" ::: "memory"); \
                       __builtin_amdgcn_sched_barrier(0); } while (0)

// 6 global_load_lds: 4 A-sweeps (64 rows) + 2 B-sweeps for K-tile at elem offset koff
#define STAGE6(bb, koff) do { \
    _Pragma("unroll") for (int t = 0; t < 4; ++t) \
        load_lds16(aS + (koff) + (size_t)(t * 64) * K, (bb) + t * 4096 + wOff); \
    _Pragma("unroll") for (int t = 0; t < 2; ++t) \
        load_lds16(bS + (koff) + (size_t)(t * 64) * K, (bb) + 16384 + t * 4096 + wOff); \
} while (0)

// 6 frag reads for k-slice p (chunk byte = ch0 ^ (p<<5))
#define RD6(bb, p, FA, FB) do { \
    const int co_ = ch0 ^ ((p) << 5); \
    FA[0] = *(const bf16x8*)((bb) + aR +    0 + co_); \
    FA[1] = *(const bf16x8*)((bb) + aR + 2048 + co_); \
    FA[2] = *(const bf16x8*)((bb) + aR + 4096 + co_); \
    FA[3] = *(const bf16x8*)((bb) + aR + 6144 + co_); \
    FB[0] = *(const bf16x8*)((bb) + bR +    0 + co_); \
    FB[1] = *(const bf16x8*)((bb) + bR + 2048 + co_); \
} while (0)

#define MM8(FA, FB) do { \
    __builtin_amdgcn_s_setprio(1); \
    acc[0][0] = __builtin_amdgcn_mfma_f32_32x32x16_bf16(FA[0], FB[0], acc[0][0], 0, 0, 0); \
    acc[1][0] = __builtin_amdgcn_mfma_f32_32x32x16_bf16(FA[1], FB[0], acc[1][0], 0, 0, 0); \
    acc[2][0] = __builtin_amdgcn_mfma_f32_32x32x16_bf16(FA[2], FB[0], acc[2][0], 0, 0, 0); \
    acc[3][0] = __builtin_amdgcn_mfma_f32_32x32x16_bf16(FA[3], FB[0], acc[3][0], 0, 0, 0); \
    acc[0][1] = __builtin_amdgcn_mfma_f32_32x32x16_bf16(FA[0], FB[1], acc[0][1], 0, 0, 0); \
    acc[1][1] = __builtin_amdgcn_mfma_f32_32x32x16_bf16(FA[1], FB[1], acc[1][1], 0, 0, 0); \
    acc[2][1] = __builtin_amdgcn_mfma_f32_32x32x16_bf16(FA[2], FB[1], acc[2][1], 0, 0, 0); \
    acc[3][1] = __builtin_amdgcn_mfma_f32_32x32x16_bf16(FA[3], FB[1], acc[3][1], 0, 0, 0); \
    __builtin_amdgcn_s_setprio(0); \
} while (0)

template <int MODE>
__global__ __launch_bounds__(256, 2) void k_gemm128(
    const u16* __restrict__ A, const u16* __restrict__ B,
    const u16* __restrict__ bias, void* __restrict__ Cv,
    int K, int ldc, int mReal, int nReal, int gx) {
    __shared__ __align__(16) char lds[49152];

    const int tid  = threadIdx.x;
    const int w    = tid >> 6, lane = tid & 63;
    const int l31  = lane & 31, hi = lane >> 5;
    const int wr   = w & 1, wc = w >> 1;            // 2x2 wave grid, per-wave 128x64

    // bijective XCD-chunked swizzle (m204 form; works for any grid size)
    const int nwg = (int)gridDim.x;
    const int q   = nwg >> 3, r = nwg & 7;
    const int xcd = (int)blockIdx.x & 7, lid = (int)blockIdx.x >> 3;
    const int wg  = (xcd < r ? xcd * (q + 1) : r * (q + 1) + (xcd - r) * q) + lid;
    const int bm  = (wg / gx) * 256;
    const int bn  = (wg % gx) * 128;

    char* const buf0 = lds;            // A [256 rows][64B] swz, B at +16384 [128][64B]
    char* const buf1 = lds + 24576;

    // staging: coalesced source rows, pre-swizzled chunk (c ^= (row>>1)&3)
    const int srcRow = tid >> 2;                     // 0..63 (+64t per sweep)
    const int srcCh  = (tid & 3) ^ ((srcRow >> 1) & 3);
    const int wOff   = (tid & ~63) << 4;             // wave slot (1 KiB per wave/sweep)

    // ds_read bases; k-slice p chunk byte = ch0 ^ (p<<5)
    const int aR  = (wr * 128 + l31) * 64;
    const int bR  = 16384 + (wc * 64 + l31) * 64;
    const int ch0 = ((hi ^ ((l31 >> 1) & 3))) << 4;

    const u16* const aS = A + (size_t)(bm + srcRow) * K + (srcCh << 3);
    const u16* const bS = B + (size_t)(bn + srcRow) * K + (srcCh << 3);

    f32x16 acc[4][2];
#pragma unroll
    for (int i = 0; i < 4; ++i)
#pragma unroll
        for (int j = 0; j < 2; ++j) acc[i][j] = (f32x16)(0.f);

    bf16x8 xa[4], xb[2], ya[4], yb[2];

    // prologue: K-tile 0 -> buf0
    STAGE6(buf0, 0);
    VMCNT0();
    BARRIER();

    const int nIt = K >> 6;            // 64-K pairs (all K are multiples of 64)
    size_t ko = 0;
#pragma unroll 1
    for (int it = 0; it < nIt; ++it) {
        STAGE6(buf1, ko + 32);           // buf1 free since B_A
        RD6(buf0, 0, xa, xb);
        RD6(buf0, 1, ya, yb);
        MM8(xa, xb);
        LGKM0(); VMCNT0(); BARRIER();    // B_B: buf0 drained, buf1 landed
        if (it + 1 < nIt) { STAGE6(buf0, ko + 64); }
        MM8(ya, yb);                     // regs only; covers buf1 turnaround
        RD6(buf1, 0, xa, xb);
        RD6(buf1, 1, ya, yb);
        MM8(xa, xb);
        LGKM0(); VMCNT0(); BARRIER();    // B_A: buf1 drained, buf0 landed
        MM8(ya, yb);
        ko += 64;
    }

    // epilogue. 32x32 C/D layout: col = lane&31, row = (reg&3) + 8*(reg>>2) + 4*hi
    float bv[2];
    if (MODE >= 1) {
#pragma unroll
        for (int ni = 0; ni < 2; ++ni) bv[ni] = b2f(bias[bn + wc * 64 + ni * 32 + l31]);
    }
#pragma unroll
    for (int mi = 0; mi < 4; ++mi) {
#pragma unroll
        for (int reg = 0; reg < 16; ++reg) {
            const int row = bm + wr * 128 + mi * 32 + (reg & 3) + 8 * (reg >> 2) + 4 * hi;
#pragma unroll
            for (int ni = 0; ni < 2; ++ni) {
                const int col = bn + wc * 64 + ni * 32 + l31;
                float vv = acc[mi][ni][reg];
                if (MODE == 0) {
                    if (row < mReal && col < nReal)
                        ((u16*)Cv)[(size_t)row * ldc + col] = f2bf(vv);
                } else if (MODE == 1) {
                    vv += bv[ni];
                    vv = vv > 0.f ? vv : 0.f;
                    ((u16*)Cv)[(size_t)row * ldc + col] = f2bf(vv);
                } else {
                    ((float*)Cv)[(size_t)row * ldc + col] = vv + bv[ni];
                }
            }
        }
    }
}

// ---------- launch ----------
// Sizes: D_IN=2048, D_H=4096, D_OUT=2048, B=4096; SIZE_N=5794, SIZE_M=2897
// Padded GEMM0 dims: M=N=5888 (23*256 / 46*128), K=2944
// Vf flat unpack offsets (elems):
//   W1 @ 0, b1 @ 8388608, W2 @ 8392704, b2 @ 25169920, W3 @ 25174016, b3 @ 33562624
extern "C" void kernel_launch(void* const* d_in, const int* in_sizes, int n_in,
                              void* d_out, int out_size, void* d_ws, size_t ws_size,
                              hipStream_t stream) {
    (void)in_sizes; (void)n_in; (void)out_size; (void)ws_size;
    const float* x  = (const float*)d_in[0];
    const float* V1 = (const float*)d_in[1];
    const float* V2 = (const float*)d_in[2];

    char* ws = (char*)d_ws;
    u16* Vf   = (u16*)(ws);                            // 5794*5794 bf16 -> 67,140,872 B
    u16* V1b  = (u16*)(ws + 67141120);                 // [5888 x 2944] bf16 = 34,668,544 B
    u16* V2bT = (u16*)(ws + 67141120 + 34668544);      // [5888 x 2944] bf16
    u16* Xb   = (u16*)(ws + 67141120 + 2 * 34668544);  // [4096 x 2048] bf16
    u16* H1   = V1b;   // dead after GEMM0
    u16* H2   = V2bT;

    k_conv_pad<<<8464, 256, 0, stream>>>(V1, V1b, 5794, 2897, 2944, 5888 * 2944 / 8);
    k_transpose_conv<<<dim3(92, 184), dim3(32, 8), 0, stream>>>(V2, V2bT, 2897, 5794, 2944);
    k_conv_pad<<<4096, 256, 0, stream>>>(x, Xb, 4096, 2048, 2048, 4096 * 2048 / 8);

    // G0: Vf = V1 @ V2  (padded 5888x5888x2944; 23x46 = 1058 tiles, 2 blocks/CU)
    k_gemm128<0><<<1058, 256, 0, stream>>>(V1b, V2bT, nullptr, Vf,
                                           2944, 5794, 5794, 5794, 46);
    // G1: H1 = relu(Xb @ W1^T + b1)   [4096x4096], K=2048 (16x32 = 512 = exactly 2/CU)
    k_gemm128<1><<<512, 256, 0, stream>>>(Xb, Vf + 0, Vf + 8388608, H1,
                                          2048, 4096, 4096, 4096, 32);
    // G2: H2 = relu(H1 @ W2^T + b2)   [4096x4096], K=4096
    k_gemm128<1><<<512, 256, 0, stream>>>(H1, Vf + 8392704, Vf + 25169920, H2,
                                          4096, 4096, 4096, 4096, 32);
    // G3: out = H2 @ W3^T + b3        [4096x2048] fp32, K=4096 (old 128^2 kernel)
    k_gemm_bt<2><<<dim3(16, 32), 256, 0, stream>>>(H2, Vf + 25174016, Vf + 33562624, d_out,
                                                   4096, 2048, 4096, 2048);
}